// Round 21
// baseline (66.370 us; speedup 1.0000x reference)
//
#include <hip/hip_runtime.h>
#include <hip/hip_bf16.h>
#include <math.h>

typedef _Float16 h16;
typedef h16   v4h __attribute__((ext_vector_type(4)));
typedef h16   h2  __attribute__((ext_vector_type(2)));
typedef float v4f __attribute__((ext_vector_type(4)));

#define T_SEQ 2048
#define BATCH 16
#define NTOK  (BATCH * T_SEQ)
#define C_DIM 64
#define N_H   4
#define HD    16
#define FF    128
#define EPS_LN 1e-5f
#define MFMA16 __builtin_amdgcn_mfma_f32_16x16x16f16
// q pre-scale: hd^-0.5 * log2(e) * 1024 (Schraudolph FMA fused into QK^T MFMA C-op)
#define QSCALE (0.25f * 1.44269504089f * 1024.0f)
#define BMAGIC (12582912.0f + 15316.0f)   // 1.5*2^23 + (15360-44)

static __device__ __forceinline__ float frcp(float x) {
#if __has_builtin(__builtin_amdgcn_rcpf)
    return __builtin_amdgcn_rcpf(x);
#else
    return 1.0f / x;
#endif
}
static __device__ __forceinline__ float frsq(float x) {
#if __has_builtin(__builtin_amdgcn_rsqf)
    return __builtin_amdgcn_rsqf(x);
#else
    return rsqrtf(x);
#endif
}
static __device__ __forceinline__ float fdot2p(h2 a, float acc) {
#if __has_builtin(__builtin_amdgcn_fdot2)
    const h2 one2 = {(h16)1.0f, (h16)1.0f};
    return __builtin_amdgcn_fdot2(a, one2, acc, false);
#else
    return acc + (float)a[0] + (float)a[1];
#endif
}
static __device__ __forceinline__ v4h cvt4(v4f f) {
    v4h r; r[0]=(h16)f[0]; r[1]=(h16)f[1]; r[2]=(h16)f[2]; r[3]=(h16)f[3];
    return r;
}
// pack low-16 (f16 bits) of two Schraudolph f32 results into one h2
static __device__ __forceinline__ h2 pkperm(float t0, float t1) {
    unsigned r = __builtin_amdgcn_perm(__builtin_bit_cast(unsigned, t1),
                                       __builtin_bit_cast(unsigned, t0),
                                       0x05040100u);
    return __builtin_bit_cast(h2, r);
}

// ---------------------------------------------------------------------------
// Weight pack: all four weight matrices -> f16 MFMA-fragment order, once.
// wp[f][lane] (v4h), element i = W[(o*16+lm)*K + kt*16+g4+i].
// Segments: wq [0,3072) | whp [3072,4096) | wh1 [4096,6144) | wh2 [6144,8192)
// ---------------------------------------------------------------------------
__global__ __launch_bounds__(256) void prep_pack(
    const float* __restrict__ Wqkv, const float* __restrict__ Wproj,
    const float* __restrict__ W1,   const float* __restrict__ W2,
    v4h* __restrict__ wp)
{
    int fid = blockIdx.x * 256 + threadIdx.x;   // 0..8191
    int lane = fid & 63;
    int lm = lane & 15, g4 = ((lane >> 4) & 3) * 4;
    int frag = fid >> 6;
    const float* src; int o, kt, K;
    if (fid < 3072)      { int f = frag;      o = f >> 2; kt = f & 3; K = 64;  src = Wqkv;  }
    else if (fid < 4096) { int f = frag - 48; o = f >> 2; kt = f & 3; K = 64;  src = Wproj; }
    else if (fid < 6144) { int f = frag - 64; o = f >> 2; kt = f & 3; K = 64;  src = W1;    }
    else                 { int f = frag - 96; o = f >> 3; kt = f & 7; K = 128; src = W2;    }
    v4f v = *(const v4f*)(src + (o*16 + lm)*K + kt*16 + g4);
    wp[fid] = cvt4(v);
}

// ---------------------------------------------------------------------------
// qkv GEMM: 1 block = 1 token-tile (coalesced 4KB x load -> LDS f16),
// 4 waves = n-split x4 over 12 output columns. Packed weights.
// q pre-scaled by QSCALE. V stored TILED: [bh][key_tile][d16][key16].
// ---------------------------------------------------------------------------
__global__ __launch_bounds__(256) void qkv_gemm(
    const float* __restrict__ x, const v4h* __restrict__ wq,
    h16* __restrict__ q, h16* __restrict__ k, h16* __restrict__ vt)
{
    int tid = threadIdx.x;
    int lane = tid & 63, w = tid >> 6;
    int lm = lane & 15, g4 = (lane >> 4) * 4;
    int tile = blockIdx.x;                  // 0..2047
    int t0 = tile * 16;
    int ng = w;                             // 3 n-values per wave

    // coalesced x load: 256 threads x 16B = the tile's contiguous 4KB
    __shared__ h16 xs[16][72];              // +8 f16 pad per row (bank spread)
    {
        v4f v = *(const v4f*)(x + (size_t)t0 * C_DIM + tid * 4);
        int r = tid >> 4;                   // row (token within tile)
        int c = (tid & 15) * 4;             // col (channel)
        *(v4h*)&xs[r][c] = cvt4(v);
    }
    __syncthreads();

    v4h af[4];
#pragma unroll
    for (int kt = 0; kt < 4; kt++)
        af[kt] = *(const v4h*)&xs[lm][kt*16 + g4];

    int b = t0 >> 11, tl = t0 & (T_SEQ - 1);
#pragma unroll
    for (int j = 0; j < 3; j++) {
        int n = ng * 3 + j;
        v4f acc = {0.f, 0.f, 0.f, 0.f};
#pragma unroll
        for (int kt = 0; kt < 4; kt++)
            acc = MFMA16(af[kt], wq[(n*4 + kt)*64 + lane], acc, 0, 0, 0);
        if (n < 4) {
            h16* qp = q + ((size_t)(b*N_H + n)*T_SEQ + tl + g4)*HD + lm;
#pragma unroll
            for (int r = 0; r < 4; r++) qp[r*HD] = (h16)(acc[r] * QSCALE);
        } else if (n < 8) {
            h16* kp = k + ((size_t)(b*N_H + (n-4))*T_SEQ + tl + g4)*HD + lm;
#pragma unroll
            for (int r = 0; r < 4; r++) kp[r*HD] = (h16)acc[r];
        } else {
            v4h pk;
#pragma unroll
            for (int r = 0; r < 4; r++) pk[r] = (h16)acc[r];
            *(v4h*)(vt + ((size_t)(b*N_H + (n-8))*(T_SEQ/16) + (tl >> 4))*256
                       + lm*16 + g4) = pk;
        }
    }
}

// ---------------------------------------------------------------------------
// Flash attention, K-split x4 with full-tile queries: NO-MAX softmax,
// Schraudolph fused into QK^T MFMA C-op, tiled V, pointer-marching.
// Block = one (bh, 256-query tile); wave w = key-quarter kq (512 keys).
// Every wave computes ALL 256 queries: 8 loads feed 128 MFMAs per kt
// (16 independent chains). 4-way additive merge: waves 1-3 publish.
// ---------------------------------------------------------------------------
__global__ __launch_bounds__(256, 2) void attn_mfma(
    const h16* __restrict__ q, const h16* __restrict__ k,
    const h16* __restrict__ vt, h16* __restrict__ a)
{
    int tid = threadIdx.x;
    int lane = tid & 63, w = tid >> 6;
    int lm = lane & 15, g4 = (lane >> 4) * 4;
    int bid = blockIdx.x;
    int W = (bid & 7) * 64 + (bid >> 3);      // XCD swizzle, bijective over 512
    int bh = W >> 3;                          // 0..63
    int q256 = W & 7;                         // 256-query tile
    int q0 = q256 * 256;
    int kq = w;                               // key quarter (512 keys)

    v4h qf[16];
#pragma unroll
    for (int j = 0; j < 16; j++)
        qf[j] = *(const v4h*)(q + ((size_t)bh*T_SEQ + q0 + j*16 + lm)*HD + g4);
    const h16* kpl = k  + ((size_t)bh*T_SEQ + kq*512 + lm)*HD + g4;
    const h16* vpl = vt + ((size_t)bh*(T_SEQ/16) + kq*32)*256 + lm*16 + g4;

    v4f acc[16];
#pragma unroll
    for (int j = 0; j < 16; j++) acc[j] = (v4f){0.f, 0.f, 0.f, 0.f};
    float l[16];
#pragma unroll
    for (int j = 0; j < 16; j++) l[j] = 0.f;
    const v4f bvec = {BMAGIC, BMAGIC, BMAGIC, BMAGIC};

    for (int kt = 0; kt < 8; kt++) {
        // ---- issue ALL tile loads first (imm offsets off marching bases) ----
        v4h kf[4], vf[4];
#pragma unroll
        for (int m = 0; m < 4; m++) {
            kf[m] = *(const v4h*)(kpl + m*256);
            vf[m] = *(const v4h*)(vpl + m*256);
        }
        kpl += 1024; vpl += 1024;
        __builtin_amdgcn_sched_barrier(0);
        // ---- 16 independent QK->perm->PV chains per m ----
#pragma unroll
        for (int m = 0; m < 4; m++) {
#pragma unroll
            for (int j = 0; j < 16; j++) {
                v4f t = MFMA16(kf[m], qf[j], bvec, 0, 0, 0);
                h2 a0 = pkperm(t[0], t[1]);
                h2 b0 = pkperm(t[2], t[3]);
                l[j] = fdot2p(a0, l[j]);
                l[j] = fdot2p(b0, l[j]);
                v4h p = __builtin_shufflevector(a0, b0, 0, 1, 2, 3);
                acc[j] = MFMA16(vf[m], p, acc[j], 0, 0, 0);
            }
        }
    }

    // per-wave finalize: group-reduce l (column-uniform)
#pragma unroll
    for (int j = 0; j < 16; j++) {
        float lj = l[j];
        lj += __shfl_xor(lj, 16, 64); lj += __shfl_xor(lj, 32, 64);
        l[j] = lj;
    }

    // K-split x4 merge via LDS: pure additive. Waves 1,2,3 publish; 0 finishes.
    __shared__ float lds[3][64][81];
    if (w >= 1) {
        float* p = lds[w - 1][lane];
#pragma unroll
        for (int j = 0; j < 16; j++) {
            p[j] = l[j];
#pragma unroll
            for (int r = 0; r < 4; r++) p[16 + j*4 + r] = acc[j][r];
        }
    }
    __syncthreads();
    if (w == 0) {
        int b = bh >> 2, h = bh & 3;
#pragma unroll
        for (int j = 0; j < 16; j++) {
            float lt = l[j] + lds[0][lane][j] + lds[1][lane][j] + lds[2][lane][j];
            float inv = frcp(lt);
            v4h o;
#pragma unroll
            for (int r = 0; r < 4; r++) {
                float av = acc[j][r] + lds[0][lane][16 + j*4 + r]
                                     + lds[1][lane][16 + j*4 + r]
                                     + lds[2][lane][16 + j*4 + r];
                o[r] = (h16)(av * inv);
            }
            *(v4h*)(a + ((size_t)(b*T_SEQ) + q0 + j*16 + lm)*C_DIM + h*HD + g4) = o;
        }
    }
}

// ---------------------------------------------------------------------------
// Fused tail, FFN split x2, packed weights, loads-first per section.
// ---------------------------------------------------------------------------
__global__ __launch_bounds__(256) void tail_fused(
    const h16* __restrict__ a, const float* __restrict__ x,
    const v4h* __restrict__ wp,
    const float* __restrict__ b1, const float* __restrict__ b2,
    const float* __restrict__ g1, const float* __restrict__ be1,
    const float* __restrict__ g2, const float* __restrict__ be2,
    float* __restrict__ out)
{
    int tid = threadIdx.x;
    int lane = tid & 63, w = tid >> 6;
    int lm = lane & 15, g4 = (lane >> 4) * 4;
    int pair = w >> 1;                 // token tile in block
    int half = w & 1;                  // ffn half
    int t0 = (blockIdx.x * 2 + pair) * 16;

    const v4h* whp = wp + 3072;
    const v4h* wh1 = wp + 4096;
    const v4h* wh2 = wp + 6144;

    v4h af[4];
#pragma unroll
    for (int kt = 0; kt < 4; kt++)
        af[kt] = *(const v4h*)(a + (size_t)(t0 + lm)*C_DIM + kt*16 + g4);

    // ---- proj + residual + LN1 (both halves compute; cheap) ----
    float rvn[4][4];
    v4h x1t[4];
    {
        v4h wf[16];
#pragma unroll
        for (int f = 0; f < 16; f++) wf[f] = whp[f*64 + lane];
        __builtin_amdgcn_sched_barrier(0);
        v4f rv[4];
#pragma unroll
        for (int cn = 0; cn < 4; cn++) {
            v4f acc = {0.f, 0.f, 0.f, 0.f};
#pragma unroll
            for (int kt = 0; kt < 4; kt++)
                acc = MFMA16(wf[cn*4 + kt], af[kt], acc, 0, 0, 0);
            v4f xr = *(const v4f*)(x + (size_t)(t0 + lm)*C_DIM + cn*16 + g4);
            rv[cn] = acc + xr;
        }
        float s = 0.f;
#pragma unroll
        for (int cn = 0; cn < 4; cn++)
#pragma unroll
            for (int i = 0; i < 4; i++) s += rv[cn][i];
        s += __shfl_xor(s, 16, 64); s += __shfl_xor(s, 32, 64);
        float mu = s * (1.f/64.f);
        float qs = 0.f;
#pragma unroll
        for (int cn = 0; cn < 4; cn++)
#pragma unroll
            for (int i = 0; i < 4; i++) { float d = rv[cn][i] - mu; qs += d*d; }
        qs += __shfl_xor(qs, 16, 64); qs += __shfl_xor(qs, 32, 64);
        float is = frsq(qs * (1.f/64.f) + EPS_LN);
#pragma unroll
        for (int cn = 0; cn < 4; cn++) {
            v4f g1v = *(const v4f*)(g1 + cn*16 + g4);
            v4f bev = *(const v4f*)(be1 + cn*16 + g4);
#pragma unroll
            for (int i = 0; i < 4; i++) {
                float vl = (rv[cn][i] - mu) * is * g1v[i] + bev[i];
                rvn[cn][i] = vl;
                x1t[cn][i] = (h16)vl;
            }
        }
    }
    __builtin_amdgcn_sched_barrier(0);

    // ---- FFN1 half + ReLU (4 of 8 nf groups) ----
    v4h ht[4];
    {
        v4h wf[16];
#pragma unroll
        for (int f = 0; f < 16; f++) wf[f] = wh1[(half*16 + f)*64 + lane];
        __builtin_amdgcn_sched_barrier(0);
#pragma unroll
        for (int j = 0; j < 4; j++) {
            int nf = half * 4 + j;
            v4f acc = {0.f, 0.f, 0.f, 0.f};
#pragma unroll
            for (int kt = 0; kt < 4; kt++)
                acc = MFMA16(wf[j*4 + kt], x1t[kt], acc, 0, 0, 0);
            v4f b1v = *(const v4f*)(b1 + nf*16 + g4);
#pragma unroll
            for (int i = 0; i < 4; i++) ht[j][i] = (h16)fmaxf(acc[i] + b1v[i], 0.f);
        }
    }
    __builtin_amdgcn_sched_barrier(0);

    // ---- FFN2 partial over this half's 64 hidden units ----
    float yp[4][4];
    {
        v4h wf[16];
#pragma unroll
        for (int cn = 0; cn < 4; cn++)
#pragma unroll
            for (int j = 0; j < 4; j++)
                wf[cn*4 + j] = wh2[(cn*8 + half*4 + j)*64 + lane];
        __builtin_amdgcn_sched_barrier(0);
#pragma unroll
        for (int cn = 0; cn < 4; cn++) {
            v4f acc = {0.f, 0.f, 0.f, 0.f};
#pragma unroll
            for (int j = 0; j < 4; j++)
                acc = MFMA16(wf[cn*4 + j], ht[j], acc, 0, 0, 0);
#pragma unroll
            for (int i = 0; i < 4; i++) yp[cn][i] = acc[i];
        }
    }

    // ---- merge halves via LDS; half 0 finishes ----
    __shared__ float lds[2][64][17];
    if (half == 1) {
        float* p = lds[pair][lane];
#pragma unroll
        for (int cn = 0; cn < 4; cn++)
#pragma unroll
            for (int i = 0; i < 4; i++) p[cn*4 + i] = yp[cn][i];
    }
    __syncthreads();
    if (half == 0) {
        const float* p = lds[pair][lane];
        float yv[4][4];
#pragma unroll
        for (int cn = 0; cn < 4; cn++) {
            v4f b2v = *(const v4f*)(b2 + cn*16 + g4);
#pragma unroll
            for (int i = 0; i < 4; i++)
                yv[cn][i] = yp[cn][i] + p[cn*4 + i] + b2v[i] + rvn[cn][i];
        }
        float s2 = 0.f;
#pragma unroll
        for (int cn = 0; cn < 4; cn++)
#pragma unroll
            for (int i = 0; i < 4; i++) s2 += yv[cn][i];
        s2 += __shfl_xor(s2, 16, 64); s2 += __shfl_xor(s2, 32, 64);
        float mu2 = s2 * (1.f/64.f);
        float qs2 = 0.f;
#pragma unroll
        for (int cn = 0; cn < 4; cn++)
#pragma unroll
            for (int i = 0; i < 4; i++) { float d = yv[cn][i] - mu2; qs2 += d*d; }
        qs2 += __shfl_xor(qs2, 16, 64); qs2 += __shfl_xor(qs2, 32, 64);
        float is2 = frsq(qs2 * (1.f/64.f) + EPS_LN);
#pragma unroll
        for (int cn = 0; cn < 4; cn++) {
            v4f g2v = *(const v4f*)(g2 + cn*16 + g4);
            v4f bev = *(const v4f*)(be2 + cn*16 + g4);
            v4f o;
#pragma unroll
            for (int i = 0; i < 4; i++) o[i] = (yv[cn][i] - mu2) * is2 * g2v[i] + bev[i];
            *(v4f*)(out + (size_t)(t0 + lm)*C_DIM + cn*16 + g4) = o;
        }
    }
}

// ---------------------------------------------------------------------------
extern "C" void kernel_launch(void* const* d_in, const int* in_sizes, int n_in,
                              void* d_out, int out_size, void* d_ws, size_t ws_size,
                              hipStream_t stream)
{
    const float* x     = (const float*)d_in[0];
    const float* Wqkv  = (const float*)d_in[1];
    const float* Wproj = (const float*)d_in[2];
    const float* W1    = (const float*)d_in[3];
    const float* b1    = (const float*)d_in[4];
    const float* W2    = (const float*)d_in[5];
    const float* b2    = (const float*)d_in[6];
    const float* g1    = (const float*)d_in[7];
    const float* be1   = (const float*)d_in[8];
    const float* g2    = (const float*)d_in[9];
    const float* be2   = (const float*)d_in[10];
    float* out = (float*)d_out;

    const size_t perQ = (size_t)BATCH * N_H * T_SEQ * HD;   // 2M elements
    h16* q   = (h16*)d_ws;
    h16* kk  = q  + perQ;
    h16* vt  = kk + perQ;
    h16* a   = vt + perQ;
    v4h* wp  = (v4h*)(a + (size_t)NTOK * C_DIM);            // 8192 frags, 64 KB

    prep_pack  <<<32,   256, 0, stream>>>(Wqkv, Wproj, W1, W2, wp);
    qkv_gemm   <<<2048, 256, 0, stream>>>(x, wp, q, kk, vt);
    attn_mfma  <<<512,  256, 0, stream>>>(q, kk, vt, a);
    tail_fused <<<1024, 256, 0, stream>>>(a, x, wp, b1, b2,
                                          g1, be1, g2, be2, out);
}

// Round 22
// 63.294 us; speedup vs baseline: 1.0486x; 1.0486x over previous
//
#include <hip/hip_runtime.h>
#include <hip/hip_bf16.h>
#include <math.h>

typedef _Float16 h16;
typedef h16   v4h __attribute__((ext_vector_type(4)));
typedef h16   h2  __attribute__((ext_vector_type(2)));
typedef float v4f __attribute__((ext_vector_type(4)));

#define T_SEQ 2048
#define BATCH 16
#define NTOK  (BATCH * T_SEQ)
#define C_DIM 64
#define N_H   4
#define HD    16
#define FF    128
#define EPS_LN 1e-5f
#define MFMA16 __builtin_amdgcn_mfma_f32_16x16x16f16
// q pre-scale: hd^-0.5 * log2(e) * 1024 (Schraudolph FMA fused into QK^T MFMA C-op)
#define QSCALE (0.25f * 1.44269504089f * 1024.0f)
#define BMAGIC (12582912.0f + 15316.0f)   // 1.5*2^23 + (15360-44)

static __device__ __forceinline__ float frcp(float x) {
#if __has_builtin(__builtin_amdgcn_rcpf)
    return __builtin_amdgcn_rcpf(x);
#else
    return 1.0f / x;
#endif
}
static __device__ __forceinline__ float frsq(float x) {
#if __has_builtin(__builtin_amdgcn_rsqf)
    return __builtin_amdgcn_rsqf(x);
#else
    return rsqrtf(x);
#endif
}
static __device__ __forceinline__ float fdot2p(h2 a, float acc) {
#if __has_builtin(__builtin_amdgcn_fdot2)
    const h2 one2 = {(h16)1.0f, (h16)1.0f};
    return __builtin_amdgcn_fdot2(a, one2, acc, false);
#else
    return acc + (float)a[0] + (float)a[1];
#endif
}
static __device__ __forceinline__ v4h cvt4(v4f f) {
    v4h r; r[0]=(h16)f[0]; r[1]=(h16)f[1]; r[2]=(h16)f[2]; r[3]=(h16)f[3];
    return r;
}
// pack low-16 (f16 bits) of two Schraudolph f32 results into one h2
static __device__ __forceinline__ h2 pkperm(float t0, float t1) {
    unsigned r = __builtin_amdgcn_perm(__builtin_bit_cast(unsigned, t1),
                                       __builtin_bit_cast(unsigned, t0),
                                       0x05040100u);
    return __builtin_bit_cast(h2, r);
}

// ---------------------------------------------------------------------------
// Weight pack: all four weight matrices -> f16 MFMA-fragment order, once.
// wp[f][lane] (v4h), element i = W[(o*16+lm)*K + kt*16+g4+i].
// Segments: wq [0,3072) | whp [3072,4096) | wh1 [4096,6144) | wh2 [6144,8192)
// ---------------------------------------------------------------------------
__global__ __launch_bounds__(256) void prep_pack(
    const float* __restrict__ Wqkv, const float* __restrict__ Wproj,
    const float* __restrict__ W1,   const float* __restrict__ W2,
    v4h* __restrict__ wp)
{
    int fid = blockIdx.x * 256 + threadIdx.x;   // 0..8191
    int lane = fid & 63;
    int lm = lane & 15, g4 = ((lane >> 4) & 3) * 4;
    int frag = fid >> 6;
    const float* src; int o, kt, K;
    if (fid < 3072)      { int f = frag;      o = f >> 2; kt = f & 3; K = 64;  src = Wqkv;  }
    else if (fid < 4096) { int f = frag - 48; o = f >> 2; kt = f & 3; K = 64;  src = Wproj; }
    else if (fid < 6144) { int f = frag - 64; o = f >> 2; kt = f & 3; K = 64;  src = W1;    }
    else                 { int f = frag - 96; o = f >> 3; kt = f & 7; K = 128; src = W2;    }
    v4f v = *(const v4f*)(src + (o*16 + lm)*K + kt*16 + g4);
    wp[fid] = cvt4(v);
}

// ---------------------------------------------------------------------------
// qkv GEMM: 1 block = 1 token-tile (coalesced 4KB x load -> LDS f16),
// 4 waves = n-split x4 over 12 output columns. Packed weights.
// q pre-scaled by QSCALE. V stored TILED: [bh][key_tile][d16][key16].
// ---------------------------------------------------------------------------
__global__ __launch_bounds__(256) void qkv_gemm(
    const float* __restrict__ x, const v4h* __restrict__ wq,
    h16* __restrict__ q, h16* __restrict__ k, h16* __restrict__ vt)
{
    int tid = threadIdx.x;
    int lane = tid & 63, w = tid >> 6;
    int lm = lane & 15, g4 = (lane >> 4) * 4;
    int tile = blockIdx.x;                  // 0..2047
    int t0 = tile * 16;
    int ng = w;                             // 3 n-values per wave

    // coalesced x load: 256 threads x 16B = the tile's contiguous 4KB
    __shared__ h16 xs[16][72];              // +8 f16 pad per row (bank spread)
    {
        v4f v = *(const v4f*)(x + (size_t)t0 * C_DIM + tid * 4);
        int r = tid >> 4;                   // row (token within tile)
        int c = (tid & 15) * 4;             // col (channel)
        *(v4h*)&xs[r][c] = cvt4(v);
    }
    __syncthreads();

    v4h af[4];
#pragma unroll
    for (int kt = 0; kt < 4; kt++)
        af[kt] = *(const v4h*)&xs[lm][kt*16 + g4];

    int b = t0 >> 11, tl = t0 & (T_SEQ - 1);
#pragma unroll
    for (int j = 0; j < 3; j++) {
        int n = ng * 3 + j;
        v4f acc = {0.f, 0.f, 0.f, 0.f};
#pragma unroll
        for (int kt = 0; kt < 4; kt++)
            acc = MFMA16(af[kt], wq[(n*4 + kt)*64 + lane], acc, 0, 0, 0);
        if (n < 4) {
            h16* qp = q + ((size_t)(b*N_H + n)*T_SEQ + tl + g4)*HD + lm;
#pragma unroll
            for (int r = 0; r < 4; r++) qp[r*HD] = (h16)(acc[r] * QSCALE);
        } else if (n < 8) {
            h16* kp = k + ((size_t)(b*N_H + (n-4))*T_SEQ + tl + g4)*HD + lm;
#pragma unroll
            for (int r = 0; r < 4; r++) kp[r*HD] = (h16)acc[r];
        } else {
            v4h pk;
#pragma unroll
            for (int r = 0; r < 4; r++) pk[r] = (h16)acc[r];
            *(v4h*)(vt + ((size_t)(b*N_H + (n-8))*(T_SEQ/16) + (tl >> 4))*256
                       + lm*16 + g4) = pk;
        }
    }
}

// ---------------------------------------------------------------------------
// Flash attention, 128-query waves: NO-MAX softmax, Schraudolph fused into
// QK^T MFMA C-op, K-split x2, tiled V, pointer-marching, loads-first.
// Block = one (bh, 256-query tile): wave w: qhalf = w&1 (128 q), khalf = w>>1.
// K/V loads amortized over 8 q-fragments; split la/lb row-sum accumulators.
// ---------------------------------------------------------------------------
__global__ __launch_bounds__(256, 2) void attn_mfma(
    const h16* __restrict__ q, const h16* __restrict__ k,
    const h16* __restrict__ vt, h16* __restrict__ a)
{
    int tid = threadIdx.x;
    int lane = tid & 63, w = tid >> 6;
    int lm = lane & 15, g4 = (lane >> 4) * 4;
    int bid = blockIdx.x;
    int W = (bid & 7) * 64 + (bid >> 3);      // XCD swizzle, bijective over 512
    int bh = W >> 3;                          // 0..63
    int q256 = W & 7;                         // 256-query tile
    int q0 = q256 * 256 + (w & 1) * 128;
    int khalf = w >> 1;

    v4h qf[8];
#pragma unroll
    for (int j = 0; j < 8; j++)
        qf[j] = *(const v4h*)(q + ((size_t)bh*T_SEQ + q0 + j*16 + lm)*HD + g4);
    const h16* kpl = k  + ((size_t)bh*T_SEQ + khalf*1024 + lm)*HD + g4;
    const h16* vpl = vt + ((size_t)bh*(T_SEQ/16) + khalf*64)*256 + lm*16 + g4;

    v4f acc[8] = {{0,0,0,0},{0,0,0,0},{0,0,0,0},{0,0,0,0},
                  {0,0,0,0},{0,0,0,0},{0,0,0,0},{0,0,0,0}};
    float la[8] = {0.f,0.f,0.f,0.f,0.f,0.f,0.f,0.f};
    float lb[8] = {0.f,0.f,0.f,0.f,0.f,0.f,0.f,0.f};
    const v4f bvec = {BMAGIC, BMAGIC, BMAGIC, BMAGIC};

    for (int kt = 0; kt < 16; kt++) {
        // ---- issue ALL tile loads first (imm offsets off marching bases) ----
        v4h kf[4], vf[4];
#pragma unroll
        for (int m = 0; m < 4; m++) {
            kf[m] = *(const v4h*)(kpl + m*256);
            vf[m] = *(const v4h*)(vpl + m*256);
        }
        kpl += 1024; vpl += 1024;
        __builtin_amdgcn_sched_barrier(0);
        // ---- 8 independent QK->perm->PV chains per m ----
#pragma unroll
        for (int m = 0; m < 4; m++) {
#pragma unroll
            for (int j = 0; j < 8; j++) {
                v4f t = MFMA16(kf[m], qf[j], bvec, 0, 0, 0);
                h2 a0 = pkperm(t[0], t[1]);
                h2 b0 = pkperm(t[2], t[3]);
                la[j] = fdot2p(a0, la[j]);
                lb[j] = fdot2p(b0, lb[j]);
                v4h p = __builtin_shufflevector(a0, b0, 0, 1, 2, 3);
                acc[j] = MFMA16(vf[m], p, acc[j], 0, 0, 0);
            }
        }
    }

    // per-wave finalize: group-reduce l (column-uniform)
    float l[8];
#pragma unroll
    for (int j = 0; j < 8; j++) {
        float lj = la[j] + lb[j];
        lj += __shfl_xor(lj, 16, 64); lj += __shfl_xor(lj, 32, 64);
        l[j] = lj;
    }

    // K-split merge via LDS: pure additive. Waves 2,3 publish; 0,1 finish.
    __shared__ float lds[2][64][41];
    if (w >= 2) {
        float* p = lds[w - 2][lane];
#pragma unroll
        for (int j = 0; j < 8; j++) {
            p[j] = l[j];
#pragma unroll
            for (int r = 0; r < 4; r++) p[8 + j*4 + r] = acc[j][r];
        }
    }
    __syncthreads();
    if (w < 2) {
        const float* p = lds[w][lane];
        int b = bh >> 2, h = bh & 3;
#pragma unroll
        for (int j = 0; j < 8; j++) {
            float inv = frcp(l[j] + p[j]);
            v4h o;
#pragma unroll
            for (int r = 0; r < 4; r++)
                o[r] = (h16)((acc[j][r] + p[8 + j*4 + r]) * inv);
            *(v4h*)(a + ((size_t)(b*T_SEQ) + q0 + j*16 + lm)*C_DIM + h*HD + g4) = o;
        }
    }
}

// ---------------------------------------------------------------------------
// Fused tail, FFN split x2, packed weights, loads-first per section.
// ---------------------------------------------------------------------------
__global__ __launch_bounds__(256) void tail_fused(
    const h16* __restrict__ a, const float* __restrict__ x,
    const v4h* __restrict__ wp,
    const float* __restrict__ b1, const float* __restrict__ b2,
    const float* __restrict__ g1, const float* __restrict__ be1,
    const float* __restrict__ g2, const float* __restrict__ be2,
    float* __restrict__ out)
{
    int tid = threadIdx.x;
    int lane = tid & 63, w = tid >> 6;
    int lm = lane & 15, g4 = (lane >> 4) * 4;
    int pair = w >> 1;                 // token tile in block
    int half = w & 1;                  // ffn half
    int t0 = (blockIdx.x * 2 + pair) * 16;

    const v4h* whp = wp + 3072;
    const v4h* wh1 = wp + 4096;
    const v4h* wh2 = wp + 6144;

    v4h af[4];
#pragma unroll
    for (int kt = 0; kt < 4; kt++)
        af[kt] = *(const v4h*)(a + (size_t)(t0 + lm)*C_DIM + kt*16 + g4);

    // ---- proj + residual + LN1 (both halves compute; cheap) ----
    float rvn[4][4];
    v4h x1t[4];
    {
        v4h wf[16];
#pragma unroll
        for (int f = 0; f < 16; f++) wf[f] = whp[f*64 + lane];
        __builtin_amdgcn_sched_barrier(0);
        v4f rv[4];
#pragma unroll
        for (int cn = 0; cn < 4; cn++) {
            v4f acc = {0.f, 0.f, 0.f, 0.f};
#pragma unroll
            for (int kt = 0; kt < 4; kt++)
                acc = MFMA16(wf[cn*4 + kt], af[kt], acc, 0, 0, 0);
            v4f xr = *(const v4f*)(x + (size_t)(t0 + lm)*C_DIM + cn*16 + g4);
            rv[cn] = acc + xr;
        }
        float s = 0.f;
#pragma unroll
        for (int cn = 0; cn < 4; cn++)
#pragma unroll
            for (int i = 0; i < 4; i++) s += rv[cn][i];
        s += __shfl_xor(s, 16, 64); s += __shfl_xor(s, 32, 64);
        float mu = s * (1.f/64.f);
        float qs = 0.f;
#pragma unroll
        for (int cn = 0; cn < 4; cn++)
#pragma unroll
            for (int i = 0; i < 4; i++) { float d = rv[cn][i] - mu; qs += d*d; }
        qs += __shfl_xor(qs, 16, 64); qs += __shfl_xor(qs, 32, 64);
        float is = frsq(qs * (1.f/64.f) + EPS_LN);
#pragma unroll
        for (int cn = 0; cn < 4; cn++) {
            v4f g1v = *(const v4f*)(g1 + cn*16 + g4);
            v4f bev = *(const v4f*)(be1 + cn*16 + g4);
#pragma unroll
            for (int i = 0; i < 4; i++) {
                float vl = (rv[cn][i] - mu) * is * g1v[i] + bev[i];
                rvn[cn][i] = vl;
                x1t[cn][i] = (h16)vl;
            }
        }
    }
    __builtin_amdgcn_sched_barrier(0);

    // ---- FFN1 half + ReLU (4 of 8 nf groups) ----
    v4h ht[4];
    {
        v4h wf[16];
#pragma unroll
        for (int f = 0; f < 16; f++) wf[f] = wh1[(half*16 + f)*64 + lane];
        __builtin_amdgcn_sched_barrier(0);
#pragma unroll
        for (int j = 0; j < 4; j++) {
            int nf = half * 4 + j;
            v4f acc = {0.f, 0.f, 0.f, 0.f};
#pragma unroll
            for (int kt = 0; kt < 4; kt++)
                acc = MFMA16(wf[j*4 + kt], x1t[kt], acc, 0, 0, 0);
            v4f b1v = *(const v4f*)(b1 + nf*16 + g4);
#pragma unroll
            for (int i = 0; i < 4; i++) ht[j][i] = (h16)fmaxf(acc[i] + b1v[i], 0.f);
        }
    }
    __builtin_amdgcn_sched_barrier(0);

    // ---- FFN2 partial over this half's 64 hidden units ----
    float yp[4][4];
    {
        v4h wf[16];
#pragma unroll
        for (int cn = 0; cn < 4; cn++)
#pragma unroll
            for (int j = 0; j < 4; j++)
                wf[cn*4 + j] = wh2[(cn*8 + half*4 + j)*64 + lane];
        __builtin_amdgcn_sched_barrier(0);
#pragma unroll
        for (int cn = 0; cn < 4; cn++) {
            v4f acc = {0.f, 0.f, 0.f, 0.f};
#pragma unroll
            for (int j = 0; j < 4; j++)
                acc = MFMA16(wf[cn*4 + j], ht[j], acc, 0, 0, 0);
#pragma unroll
            for (int i = 0; i < 4; i++) yp[cn][i] = acc[i];
        }
    }

    // ---- merge halves via LDS; half 0 finishes ----
    __shared__ float lds[2][64][17];
    if (half == 1) {
        float* p = lds[pair][lane];
#pragma unroll
        for (int cn = 0; cn < 4; cn++)
#pragma unroll
            for (int i = 0; i < 4; i++) p[cn*4 + i] = yp[cn][i];
    }
    __syncthreads();
    if (half == 0) {
        const float* p = lds[pair][lane];
        float yv[4][4];
#pragma unroll
        for (int cn = 0; cn < 4; cn++) {
            v4f b2v = *(const v4f*)(b2 + cn*16 + g4);
#pragma unroll
            for (int i = 0; i < 4; i++)
                yv[cn][i] = yp[cn][i] + p[cn*4 + i] + b2v[i] + rvn[cn][i];
        }
        float s2 = 0.f;
#pragma unroll
        for (int cn = 0; cn < 4; cn++)
#pragma unroll
            for (int i = 0; i < 4; i++) s2 += yv[cn][i];
        s2 += __shfl_xor(s2, 16, 64); s2 += __shfl_xor(s2, 32, 64);
        float mu2 = s2 * (1.f/64.f);
        float qs2 = 0.f;
#pragma unroll
        for (int cn = 0; cn < 4; cn++)
#pragma unroll
            for (int i = 0; i < 4; i++) { float d = yv[cn][i] - mu2; qs2 += d*d; }
        qs2 += __shfl_xor(qs2, 16, 64); qs2 += __shfl_xor(qs2, 32, 64);
        float is2 = frsq(qs2 * (1.f/64.f) + EPS_LN);
#pragma unroll
        for (int cn = 0; cn < 4; cn++) {
            v4f g2v = *(const v4f*)(g2 + cn*16 + g4);
            v4f bev = *(const v4f*)(be2 + cn*16 + g4);
            v4f o;
#pragma unroll
            for (int i = 0; i < 4; i++) o[i] = (yv[cn][i] - mu2) * is2 * g2v[i] + bev[i];
            *(v4f*)(out + (size_t)(t0 + lm)*C_DIM + cn*16 + g4) = o;
        }
    }
}

// ---------------------------------------------------------------------------
extern "C" void kernel_launch(void* const* d_in, const int* in_sizes, int n_in,
                              void* d_out, int out_size, void* d_ws, size_t ws_size,
                              hipStream_t stream)
{
    const float* x     = (const float*)d_in[0];
    const float* Wqkv  = (const float*)d_in[1];
    const float* Wproj = (const float*)d_in[2];
    const float* W1    = (const float*)d_in[3];
    const float* b1    = (const float*)d_in[4];
    const float* W2    = (const float*)d_in[5];
    const float* b2    = (const float*)d_in[6];
    const float* g1    = (const float*)d_in[7];
    const float* be1   = (const float*)d_in[8];
    const float* g2    = (const float*)d_in[9];
    const float* be2   = (const float*)d_in[10];
    float* out = (float*)d_out;

    const size_t perQ = (size_t)BATCH * N_H * T_SEQ * HD;   // 2M elements
    h16* q   = (h16*)d_ws;
    h16* kk  = q  + perQ;
    h16* vt  = kk + perQ;
    h16* a   = vt + perQ;
    v4h* wp  = (v4h*)(a + (size_t)NTOK * C_DIM);            // 8192 frags, 64 KB

    prep_pack  <<<32,   256, 0, stream>>>(Wqkv, Wproj, W1, W2, wp);
    qkv_gemm   <<<2048, 256, 0, stream>>>(x, wp, q, kk, vt);
    attn_mfma  <<<512,  256, 0, stream>>>(q, kk, vt, a);
    tail_fused <<<1024, 256, 0, stream>>>(a, x, wp, b1, b2,
                                          g1, be1, g2, be2, out);
}